// Round 1
// baseline (5206.167 us; speedup 1.0000x reference)
//
#include <hip/hip_runtime.h>

// EKF with learned dynamics/measurement residuals.
// One block per batch element (B=256), full T=512 scan inside the kernel.
// 256 threads = 4 waves; per-step phase pipeline with ~14 __syncthreads.
// Tangent (Jacobian) matmuls: k-major LDS fragments (stride 16, float4
// broadcast reads) x per-thread register-resident weight columns of the
// two 64x64 matrices (dW1, mW1) -> no per-MAC LDS vector reads.

#define NB 256
#define NT 512
#define EKF_DT 0.01f
#define PM_OFF (NB * NT * 12)
#define COV_OFF (NB * NT * (12 + 9))

__launch_bounds__(256, 1)
__global__ void ekf_kernel(
    const float* __restrict__ ctrl, const float* __restrict__ meas,
    const float* __restrict__ x0g, const float* __restrict__ P0g,
    const float* __restrict__ Qg, const float* __restrict__ Rg,
    const float* __restrict__ dW0, const float* __restrict__ db0,
    const float* __restrict__ dW1, const float* __restrict__ db1,
    const float* __restrict__ dW2, const float* __restrict__ db2,
    const float* __restrict__ dW3, const float* __restrict__ db3,
    const float* __restrict__ mW0, const float* __restrict__ mb0,
    const float* __restrict__ mW1, const float* __restrict__ mb1,
    const float* __restrict__ mW2, const float* __restrict__ mb2,
    float* __restrict__ out)
{
  const int b = blockIdx.x;
  const int tid = threadIdx.x;
  const int lane = tid & 63;
  const int wid = tid >> 6;

  // weights staged in LDS (dW1/mW1 live in per-thread registers instead)
  __shared__ float sW0[16 * 64];
  __shared__ float sW2[64 * 32];
  __shared__ float sW3[32 * 12];
  __shared__ float sM0[12 * 64];
  __shared__ float sM2[64 * 9];
  __shared__ float sB0[64], sB1[64], sB2[32], sB3[12];
  __shared__ float sN0[64], sN1[64], sN2[9];

  // k-major tangent fragments, stride 16 (rows 12..15 unused padding)
  __shared__ __align__(16) float R1t[64 * 16]; // T1t / U1t ; K rows in [0..108)
  __shared__ __align__(16) float R2t[64 * 16]; // T2t / U2t ; S in [0..81)
  __shared__ __align__(16) float R3t[32 * 16]; // T3t ; PHt in [0..108)
  __shared__ float FH[144];   // F, later H (rows < 9)
  __shared__ float FPA[144];  // FP, later HP, later A = I-KH
  __shared__ float Pm[144], Pp[144];
  __shared__ float xs[12], xp[12], r4v[12], dv9[9];
  __shared__ float A1[64], A1d[64], A2[64], A2d[64], A3[32], A3d[32];

  for (int i = tid; i < 16 * 64; i += 256) sW0[i] = dW0[i];
  for (int i = tid; i < 64 * 32; i += 256) sW2[i] = dW2[i];
  for (int i = tid; i < 32 * 12; i += 256) sW3[i] = dW3[i];
  for (int i = tid; i < 12 * 64; i += 256) sM0[i] = mW0[i];
  for (int i = tid; i < 64 * 9; i += 256) sM2[i] = mW2[i];
  if (tid < 64) { sB0[tid] = db0[tid]; sB1[tid] = db1[tid]; sN0[tid] = mb0[tid]; sN1[tid] = mb1[tid]; }
  if (tid < 32) sB2[tid] = db2[tid];
  if (tid < 12) { sB3[tid] = db3[tid]; xs[tid] = x0g[b * 12 + tid]; }
  if (tid < 9)  sN2[tid] = mb2[tid];
  if (tid < 144) Pm[tid] = P0g[b * 144 + tid];

  // per-thread register copy of column `lane` of dW1 and mW1
  float w1c[64], m1c[64];
  #pragma unroll
  for (int k = 0; k < 64; ++k) { w1c[k] = dW1[k * 64 + lane]; m1c[k] = mW1[k * 64 + lane]; }
  __syncthreads();

  #pragma unroll 1
  for (int t = 0; t < NT; ++t) {
    if (t > 0) {
      // ---- B: L1 = tanh([x,u] W0 + b0) (wave 0) ----
      if (wid == 0) {
        const float* cu = ctrl + (size_t)(b * NT + t) * 4;
        float pre = sB0[lane];
        #pragma unroll
        for (int k = 0; k < 12; ++k) pre += xs[k] * sW0[k * 64 + lane];
        pre += cu[0] * sW0[12 * 64 + lane];
        pre += cu[1] * sW0[13 * 64 + lane];
        pre += cu[2] * sW0[14 * 64 + lane];
        pre += cu[3] * sW0[15 * 64 + lane];
        const float l = tanhf(pre);
        A1[lane] = l; A1d[lane] = 1.f - l * l;
      }
      __syncthreads();
      // ---- C: L2 (wave 0) ; T1t[k][i] = D1[k]*W0[i][k] (waves 1-3) ----
      if (wid == 0) {
        float pre = sB1[lane];
        #pragma unroll
        for (int k = 0; k < 64; ++k) pre += A1[k] * w1c[k];
        const float l = tanhf(pre);
        A2[lane] = l; A2d[lane] = 1.f - l * l;
      } else {
        const int q = tid - 64, k = q & 63, j = q >> 6; // j = row-quad 0..2
        const float d = A1d[k];
        float4 o;
        o.x = d * sW0[(4 * j + 0) * 64 + k];
        o.y = d * sW0[(4 * j + 1) * 64 + k];
        o.z = d * sW0[(4 * j + 2) * 64 + k];
        o.w = d * sW0[(4 * j + 3) * 64 + k];
        *(float4*)&R1t[k * 16 + 4 * j] = o;
      }
      __syncthreads();
      // ---- D: T2 rows 4w..4w+3 (waves 0-2, reg weight col) ; L3 (wave 3) ----
      if (wid < 3) {
        float a0 = 0, a1 = 0, a2 = 0, a3 = 0;
        #pragma unroll
        for (int k = 0; k < 64; ++k) {
          const float4 tt = *(const float4*)&R1t[k * 16 + 4 * wid];
          const float w = w1c[k];
          a0 += tt.x * w; a1 += tt.y * w; a2 += tt.z * w; a3 += tt.w * w;
        }
        const float d = A2d[lane];
        float4 o; o.x = a0 * d; o.y = a1 * d; o.z = a2 * d; o.w = a3 * d;
        *(float4*)&R2t[lane * 16 + 4 * wid] = o;
      } else if (lane < 32) {
        float pre = sB2[lane];
        #pragma unroll
        for (int k = 0; k < 64; ++k) pre += A2[k] * sW2[k * 32 + lane];
        const float l = tanhf(pre);
        A3[lane] = l; A3d[lane] = 1.f - l * l;
      }
      __syncthreads();
      // ---- E: T3 (waves 0-2, k split across half-waves) ; r4 (wave 3) ----
      if (wid < 3) {
        const int c = lane & 31, h = lane >> 5;
        float a0 = 0, a1 = 0, a2 = 0, a3 = 0;
        #pragma unroll
        for (int kk = 0; kk < 32; ++kk) {
          const int k = h * 32 + kk;
          const float4 tt = *(const float4*)&R2t[k * 16 + 4 * wid];
          const float w = sW2[k * 32 + c];
          a0 += tt.x * w; a1 += tt.y * w; a2 += tt.z * w; a3 += tt.w * w;
        }
        a0 += __shfl_down(a0, 32); a1 += __shfl_down(a1, 32);
        a2 += __shfl_down(a2, 32); a3 += __shfl_down(a3, 32);
        if (h == 0) {
          const float d = A3d[c];
          float4 o; o.x = a0 * d; o.y = a1 * d; o.z = a2 * d; o.w = a3 * d;
          *(float4*)&R3t[c * 16 + 4 * wid] = o;
        }
      } else if (lane < 12) {
        float acc = sB3[lane];
        #pragma unroll
        for (int k = 0; k < 32; ++k) acc += A3[k] * sW3[k * 12 + lane];
        r4v[lane] = acc;
      }
      __syncthreads();
      // ---- F: F[j][i] = d f_j / d s_i ; xp = f(x,u) ----
      if (tid < 144) {
        const int i = tid / 12, j = tid - 12 * i;
        float acc = 0.f;
        #pragma unroll
        for (int k = 0; k < 32; ++k) acc += R3t[k * 16 + i] * sW3[k * 12 + j];
        float v = acc + ((i == j) ? 1.f : 0.f);
        if (((j < 3) || (j >= 6 && j < 9)) && (i == j + 3)) v += EKF_DT;
        FH[j * 12 + i] = v;
      } else if (tid < 156) {
        const int j = tid - 144;
        const float drift = ((j < 3) || (j >= 6 && j < 9)) ? xs[j + 3] : 0.f;
        xp[j] = xs[j] + EKF_DT * drift + r4v[j];
      }
      __syncthreads();
      // ---- G: FP = F @ P ; m1 = relu(xp mW0 + b) ----
      if (tid < 144) {
        const int j = tid / 12, c = tid - 12 * j;
        float acc = 0.f;
        #pragma unroll
        for (int m = 0; m < 12; ++m) acc += FH[j * 12 + m] * Pm[m * 12 + c];
        FPA[tid] = acc;
      } else if (tid >= 160 && tid < 224) {
        const int c = tid - 160;
        float pre = sN0[c];
        #pragma unroll
        for (int k = 0; k < 12; ++k) pre += xp[k] * sM0[k * 64 + c];
        A1[c] = fmaxf(pre, 0.f);
        A1d[c] = (pre > 0.f) ? 1.f : 0.f;
      }
      __syncthreads();
      // ---- H: Pp = FP F^T + Q ; U1t ; m2 (wave 3, reg weight col) ----
      if (tid < 144) {
        const int j = tid / 12, c = tid - 12 * j;
        float acc = Qg[tid];
        #pragma unroll
        for (int m = 0; m < 12; ++m) acc += FPA[j * 12 + m] * FH[c * 12 + m];
        Pp[tid] = acc;
      }
      if (tid < 192) {
        const int k = tid & 63, j = tid >> 6;
        const float d = A1d[k];
        float4 o;
        o.x = d * sM0[(4 * j + 0) * 64 + k];
        o.y = d * sM0[(4 * j + 1) * 64 + k];
        o.z = d * sM0[(4 * j + 2) * 64 + k];
        o.w = d * sM0[(4 * j + 3) * 64 + k];
        *(float4*)&R1t[k * 16 + 4 * j] = o;
      } else {
        const int c = lane;
        float pre = sN1[c];
        #pragma unroll
        for (int k = 0; k < 64; ++k) pre += A1[k] * m1c[k];
        A2[c] = fmaxf(pre, 0.f);
        A2d[c] = (pre > 0.f) ? 1.f : 0.f;
      }
      __syncthreads();
    } else {
      // ---- t == 0: xp = x0, Pp = P0, m1 ----
      if (tid < 12) xp[tid] = xs[tid];
      if (tid >= 32 && tid < 176) Pp[tid - 32] = Pm[tid - 32];
      if (wid == 3) {
        const int c = lane;
        float pre = sN0[c];
        #pragma unroll
        for (int k = 0; k < 12; ++k) pre += xs[k] * sM0[k * 64 + c];
        A1[c] = fmaxf(pre, 0.f);
        A1d[c] = (pre > 0.f) ? 1.f : 0.f;
      }
      __syncthreads();
      // ---- U1t ; m2 ----
      if (tid < 192) {
        const int k = tid & 63, j = tid >> 6;
        const float d = A1d[k];
        float4 o;
        o.x = d * sM0[(4 * j + 0) * 64 + k];
        o.y = d * sM0[(4 * j + 1) * 64 + k];
        o.z = d * sM0[(4 * j + 2) * 64 + k];
        o.w = d * sM0[(4 * j + 3) * 64 + k];
        *(float4*)&R1t[k * 16 + 4 * j] = o;
      } else {
        const int c = lane;
        float pre = sN1[c];
        #pragma unroll
        for (int k = 0; k < 64; ++k) pre += A1[k] * m1c[k];
        A2[c] = fmaxf(pre, 0.f);
        A2d[c] = (pre > 0.f) ? 1.f : 0.f;
      }
      __syncthreads();
    }
    // ---- I: U2 (waves 0-2) ; zp, dv, pred_meas out (wave 3) ----
    if (wid < 3) {
      float a0 = 0, a1 = 0, a2 = 0, a3 = 0;
      #pragma unroll
      for (int k = 0; k < 64; ++k) {
        const float4 tt = *(const float4*)&R1t[k * 16 + 4 * wid];
        const float w = m1c[k];
        a0 += tt.x * w; a1 += tt.y * w; a2 += tt.z * w; a3 += tt.w * w;
      }
      const float d = A2d[lane];
      float4 o; o.x = a0 * d; o.y = a1 * d; o.z = a2 * d; o.w = a3 * d;
      *(float4*)&R2t[lane * 16 + 4 * wid] = o;
    } else if (lane < 9) {
      float pre = sN2[lane];
      #pragma unroll
      for (int k = 0; k < 64; ++k) pre += A2[k] * sM2[k * 9 + lane];
      const float zpv = xp[lane] + pre;
      const float zv = meas[(size_t)(b * NT + t) * 9 + lane];
      dv9[lane] = zv - zpv;
      out[PM_OFF + (b * NT + t) * 9 + lane] = zpv;
    }
    __syncthreads();
    // ---- J: H[j][i] = delta + sum_c U2[i][c] mW2[c][j] ----
    if (tid < 108) {
      const int i = tid / 9, j = tid - 9 * i;
      float acc = 0.f;
      #pragma unroll
      for (int k = 0; k < 64; ++k) acc += R2t[k * 16 + i] * sM2[k * 9 + j];
      FH[j * 12 + i] = acc + ((i == j) ? 1.f : 0.f);
    }
    __syncthreads();
    // ---- K: HP = H @ Pp ; PHt = Pp @ H^T ----
    if (tid < 108) {
      const int j = tid / 12, c = tid - 12 * j;
      float acc = 0.f;
      #pragma unroll
      for (int m = 0; m < 12; ++m) acc += FH[j * 12 + m] * Pp[m * 12 + c];
      FPA[tid] = acc;
    } else if (tid >= 128 && tid < 236) {
      const int q = tid - 128, j = q / 9, c = q - 9 * j;
      float acc = 0.f;
      #pragma unroll
      for (int m = 0; m < 12; ++m) acc += Pp[j * 12 + m] * FH[c * 12 + m];
      R3t[q] = acc;
    }
    __syncthreads();
    // ---- L: S = HP H^T + R ----
    if (tid < 81) {
      const int a = tid / 9, c = tid - 9 * a;
      float acc = Rg[tid];
      #pragma unroll
      for (int m = 0; m < 12; ++m) acc += FPA[a * 12 + m] * FH[c * 12 + m];
      R2t[tid] = acc;
    }
    __syncthreads();
    // ---- M: K rows via per-thread register Cholesky (12 threads) ----
    if (tid < 12) {
      float Lm[45];
      #pragma unroll
      for (int i = 0; i < 9; ++i)
        #pragma unroll
        for (int j = 0; j <= i; ++j)
          Lm[(i * (i + 1)) / 2 + j] = R2t[i * 9 + j];
      #pragma unroll
      for (int k = 0; k < 9; ++k) {
        float d = Lm[(k * (k + 1)) / 2 + k];
        #pragma unroll
        for (int j = 0; j < k; ++j) { const float v = Lm[(k * (k + 1)) / 2 + j]; d -= v * v; }
        d = sqrtf(d);
        Lm[(k * (k + 1)) / 2 + k] = d;
        const float inv = 1.f / d;
        #pragma unroll
        for (int i2 = k + 1; i2 < 9; ++i2) {
          float v = Lm[(i2 * (i2 + 1)) / 2 + k];
          #pragma unroll
          for (int j = 0; j < k; ++j) v -= Lm[(i2 * (i2 + 1)) / 2 + j] * Lm[(k * (k + 1)) / 2 + j];
          Lm[(i2 * (i2 + 1)) / 2 + k] = v * inv;
        }
      }
      float y[9];
      #pragma unroll
      for (int i = 0; i < 9; ++i) {
        float v = R3t[tid * 9 + i];
        #pragma unroll
        for (int j = 0; j < i; ++j) v -= Lm[(i * (i + 1)) / 2 + j] * y[j];
        y[i] = v / Lm[(i * (i + 1)) / 2 + i];
      }
      #pragma unroll
      for (int i = 8; i >= 0; --i) {
        float v = y[i];
        #pragma unroll
        for (int j = i + 1; j < 9; ++j) v -= Lm[(j * (j + 1)) / 2 + i] * y[j];
        y[i] = v / Lm[(i * (i + 1)) / 2 + i];
      }
      #pragma unroll
      for (int i = 0; i < 9; ++i) R1t[tid * 9 + i] = y[i];
    }
    __syncthreads();
    // ---- N: A = I - K H ; x_new = xp + K (z - zp) ----
    if (tid < 144) {
      const int j = tid / 12, i = tid - 12 * j;
      float acc = (i == j) ? 1.f : 0.f;
      #pragma unroll
      for (int c = 0; c < 9; ++c) acc -= R1t[j * 9 + c] * FH[c * 12 + i];
      FPA[tid] = acc;
    } else if (tid < 156) {
      const int j = tid - 144;
      float acc = xp[j];
      #pragma unroll
      for (int c = 0; c < 9; ++c) acc += R1t[j * 9 + c] * dv9[c];
      xs[j] = acc;
    }
    __syncthreads();
    // ---- O: P_new = A @ Pp ; write cov + est outputs ----
    if (tid < 144) {
      const int j = tid / 12, c = tid - 12 * j;
      float acc = 0.f;
      #pragma unroll
      for (int m = 0; m < 12; ++m) acc += FPA[j * 12 + m] * Pp[m * 12 + c];
      Pm[tid] = acc;
      out[COV_OFF + (b * NT + t) * 144 + tid] = acc;
    } else if (tid >= 160 && tid < 172) {
      out[(b * NT + t) * 12 + (tid - 160)] = xs[tid - 160];
    }
    __syncthreads();
  }
}

extern "C" void kernel_launch(void* const* d_in, const int* in_sizes, int n_in,
                              void* d_out, int out_size, void* d_ws, size_t ws_size,
                              hipStream_t stream) {
  (void)in_sizes; (void)n_in; (void)d_ws; (void)ws_size; (void)out_size;
  // d_in: 0 states(unused) 1 controls 2 measurements 3 init_state 4 init_cov
  //       5 Q 6 R 7..14 dW0,db0..dW3,db3 15..20 mW0,mb0..mW2,mb2
  ekf_kernel<<<NB, 256, 0, stream>>>(
      (const float*)d_in[1], (const float*)d_in[2],
      (const float*)d_in[3], (const float*)d_in[4],
      (const float*)d_in[5], (const float*)d_in[6],
      (const float*)d_in[7], (const float*)d_in[8],
      (const float*)d_in[9], (const float*)d_in[10],
      (const float*)d_in[11], (const float*)d_in[12],
      (const float*)d_in[13], (const float*)d_in[14],
      (const float*)d_in[15], (const float*)d_in[16],
      (const float*)d_in[17], (const float*)d_in[18],
      (const float*)d_in[19], (const float*)d_in[20],
      (float*)d_out);
}